// Round 8
// baseline (409.993 us; speedup 1.0000x reference)
//
#include <hip/hip_runtime.h>
#include <stdint.h>

// out[b][o] = clamp((sum_k x[b][k]*W[o][k] + t[o]) >> (-n[o]), act_min[o], act_max[o])
// B=8192, IN=4096, OUT=4096. x,W arrive int32; harness reads d_out as int32.
//
// R18: decorrelation test. R10-R17 exonerated L2 BW, waves/SIMD, setprio,
// barrier placement, vm distance (R16: 4-phase-old loads, still 1250 cy/set),
// LDS port (R17: 40KB/set < MFMA window, still 1250). Last shared factor: one
// barrier domain per CU -- all waves wait together, nothing feeds the MFMA
// pipe during collective drains. Now: wave tile 64x64 (acc=64), 8-wave block
// = 256x128 tile, __launch_bounds__(512,4) -> 2 INDEPENDENT blocks/CU, 4
// waves/SIMD from 2 barrier domains that interleave phase-offset. Schedule =
// R17 verbatim (A glds dist-4/6buf, B direct-to-reg dist-2, vmcnt(3)).

#define BDIM 8192
#define INDIM 4096
#define OUTDIM 4096

typedef __attribute__((ext_vector_type(4))) int I4;
typedef __attribute__((ext_vector_type(16))) int I16;

// ---------------- pack: int32 -> int8 fragment order, LDS transpose ----------
// Fragment layout: byte off = ((m32*128 + kb)*64 + lane)*16 + b,
// where row = m32*32 + (lane&31), k = kb*32 + (lane>>5)*16 + b.
__global__ __launch_bounds__(256) void pack_lds(const int* __restrict__ x,
                                                const int* __restrict__ W,
                                                uint32_t* __restrict__ xp,
                                                uint32_t* __restrict__ wp) {
    __shared__ uint32_t sb[8192];  // 32 KB
    const int tid = threadIdx.x;
    const int bid = blockIdx.x;
    const int* src;
    uint32_t* dst;
    if (bid < 1024) {
        const int m32 = bid >> 2, q = bid & 3;
        src = x + (size_t)m32 * 32 * INDIM + q * 1024;
        dst = xp + (size_t)m32 * 32768 + q * 8192;
    } else {
        const int v = bid - 1024;
        const int n32 = v >> 2, q = v & 3;
        src = W + (size_t)n32 * 32 * INDIM + q * 1024;
        dst = wp + (size_t)n32 * 32768 + q * 8192;
    }
    const int kb_l = tid >> 3;                 // local kb (k/32 within chunk)
    const int lane_hi = ((tid >> 2) & 1) << 5; // (k>>4)&1 -> lane bit 5
    const int bslot = tid & 3;                 // byte-word slot within lane's 16B
#pragma unroll 4
    for (int rr = 0; rr < 32; ++rr) {
        int4 a = *(const int4*)(src + (size_t)rr * INDIM + tid * 4);
        uint32_t v = ((uint32_t)a.x & 255u) | (((uint32_t)a.y & 255u) << 8)
                   | (((uint32_t)a.z & 255u) << 16) | (((uint32_t)a.w & 255u) << 24);
        uint32_t idx = (uint32_t)(kb_l * 256 + (rr + lane_hi) * 4 + bslot);
        idx ^= ((idx >> 8) & 7u) << 2;  // XOR-swizzle: 16-way -> 2-way (free)
        sb[idx] = v;
    }
    __syncthreads();
#pragma unroll
    for (int it = 0; it < 8; ++it) {
        uint32_t idx = (uint32_t)(it * 1024 + tid * 4);
        idx ^= ((idx >> 8) & 7u) << 2;
        uint4 vv = *(const uint4*)&sb[idx];
        *(uint4*)(dst + it * 1024 + tid * 4) = vv;
    }
}

// ------- GEMM: 8 waves (4x2 of 64x64), 256x128 tile, 2 indep blocks/CU ------
__device__ __forceinline__ void glds16(const void* g, void* l) {
    __builtin_amdgcn_global_load_lds((__attribute__((address_space(1))) void*)g,
                                     (__attribute__((address_space(3))) void*)l,
                                     16, 0, 0);
}

#define VMW3() asm volatile("s_waitcnt vmcnt(3)" ::: "memory")
#define VMW2() asm volatile("s_waitcnt vmcnt(2)" ::: "memory")
#define VMW0() asm volatile("s_waitcnt vmcnt(0)" ::: "memory")
#define BARRIER()                          \
    do {                                   \
        __builtin_amdgcn_s_barrier();      \
        asm volatile("" ::: "memory");     \
    } while (0)
#define SCHEDB() __builtin_amdgcn_sched_barrier(0)

// stage A-subtile w of set SETK into buffer BUF (0..5): 1 glds per wave
#define STAGE_A(SETK, BUF) \
    glds16(ga + (size_t)(SETK) * 1024, lds_raw + (BUF) * 8192 + w * 1024)

// load this wave's 2 B-subtiles of set SETK into reg pair LB
#define LOADB(SETK, LB)                                                           \
    do {                                                                          \
        const uint8_t* p0_ = gb0 + (size_t)(SETK) * 1024;                         \
        const uint8_t* p1_ = gb1 + (size_t)(SETK) * 1024;                         \
        asm volatile("global_load_dwordx4 %0, %1, off"                            \
                     : "=&v"(LB[0]) : "v"(p0_));                                  \
        asm volatile("global_load_dwordx4 %0, %1, off"                            \
                     : "=&v"(LB[1]) : "v"(p1_));                                  \
    } while (0)

// read this wave's 2 A-fragments of one set from buffer BUF (compile-time 0..5)
#define FRAG_READA(FA, BUF)                                                       \
    do {                                                                          \
        const uint8_t* lb_ = lds_raw + (BUF) * 8192 + lane * 16;                  \
        _Pragma("unroll")                                                         \
        for (int i_ = 0; i_ < 2; ++i_)                                            \
            FA[i_] = *(const I4*)(lb_ + (wr2 + i_) * 1024);                       \
    } while (0)

#define MFMA_SET(FA, FB)                                                          \
    do {                                                                          \
        __builtin_amdgcn_s_setprio(1);                                            \
        _Pragma("unroll")                                                         \
        for (int i_ = 0; i_ < 2; ++i_)                                            \
            _Pragma("unroll")                                                     \
            for (int j_ = 0; j_ < 2; ++j_)                                        \
                acc[i_][j_] = __builtin_amdgcn_mfma_i32_32x32x32_i8(              \
                    FA[i_], FB[j_], acc[i_][j_], 0, 0, 0);                        \
        __builtin_amdgcn_s_setprio(0);                                            \
    } while (0)

// Phase P: wait(vmcnt) -> barrier -> sched fence -> {stage A(P+4), load B(P+2),
// read A-frags(P+1)} overlapping MFMA(P).
#define PH_FULL(VMW_STMT, SSET, SBUF, LSET, LB, RBUF, RAF, MAF, MB)               \
    do {                                                                          \
        VMW_STMT;                                                                 \
        BARRIER();                                                                \
        SCHEDB();                                                                 \
        STAGE_A(SSET, SBUF);                                                      \
        LOADB(LSET, LB);                                                          \
        FRAG_READA(RAF, RBUF);                                                    \
        MFMA_SET(MAF, MB);                                                        \
    } while (0)

#define PH_NOSTAGE(VMW_STMT, LSET, LB, RBUF, RAF, MAF, MB)                        \
    do {                                                                          \
        VMW_STMT;                                                                 \
        BARRIER();                                                                \
        SCHEDB();                                                                 \
        LOADB(LSET, LB);                                                          \
        FRAG_READA(RAF, RBUF);                                                    \
        MFMA_SET(MAF, MB);                                                        \
    } while (0)

__global__ __launch_bounds__(512, 4) void gemm_lds(
    const uint8_t* __restrict__ Xp,   // fragment-ordered
    const uint8_t* __restrict__ Wp,   // fragment-ordered
    const int* __restrict__ t, const int* __restrict__ nsh,
    const int* __restrict__ amin, const int* __restrict__ amax,
    int* __restrict__ out) {

    const int bn = blockIdx.x;       // 0..31 (OUT tiles of 128) — fast axis
    const int bm = blockIdx.y;       // 0..31 (batch tiles of 256)
    const int tid = threadIdx.x;
    const int lane = tid & 63;
    const int w = tid >> 6;          // wave 0..7
    const int wr = w >> 1;           // wave row (0..3): rows wr*64..+64
    const int wc = w & 1;            // wave col (0..1): cols wc*64..+64
    const int wr2 = wr * 2;
    const int wc2 = wc * 2;

    __shared__ uint8_t lds_raw[49152];  // 6 buffers x 8 A-subtiles x 1 KB

    // A: wave w stages subtile w (rows bm*256 + w*32)
    const uint8_t* ga = Xp + ((size_t)(bm * 8 + w) << 17) + lane * 16;
    // B: this wave's two column-subtiles, loaded direct to regs
    const uint8_t* gb0 = Wp + ((size_t)(bn * 4 + wc2 + 0) << 17) + lane * 16;
    const uint8_t* gb1 = Wp + ((size_t)(bn * 4 + wc2 + 1) << 17) + lane * 16;

    I16 acc[2][2];
#pragma unroll
    for (int i = 0; i < 2; ++i)
#pragma unroll
        for (int j = 0; j < 2; ++j)
#pragma unroll
            for (int r = 0; r < 16; ++r) acc[i][j][r] = 0;

    I4 af0[2], af1[2], b0[2], b1[2], b2[2];

    // prologue: stage A sets 0..3 (bufs 0..3), load B sets 0,1 -> b0,b1;
    // drain once (one-time), publish, read A-frags of set 0.
    STAGE_A(0, 0);
    STAGE_A(1, 1);
    STAGE_A(2, 2);
    STAGE_A(3, 3);
    LOADB(0, b0);
    LOADB(1, b1);
    VMW0();
    BARRIER();
    SCHEDB();
    FRAG_READA(af0, 0);

    // steady state, phase P: vmcnt(3) (= keep newest phase's 3 issues) drains
    // through phase P-2 -> confirms A(P+1) (staged P-3) and B(P) (loaded P-2).
    // Then stage A(P+4), load B(P+2), read frags(P+1), MFMA(P).
#pragma unroll 1
    for (int kk = 0; kk < 120; kk += 6) {
        PH_FULL(VMW3(), kk + 4, 4, kk + 2, b2, 1, af1, af0, b0);  // P=kk+0
        PH_FULL(VMW3(), kk + 5, 5, kk + 3, b0, 2, af0, af1, b1);  // P=kk+1
        PH_FULL(VMW3(), kk + 6, 0, kk + 4, b1, 3, af1, af0, b2);  // P=kk+2
        PH_FULL(VMW3(), kk + 7, 1, kk + 5, b2, 4, af0, af1, b0);  // P=kk+3
        PH_FULL(VMW3(), kk + 8, 2, kk + 6, b0, 5, af1, af0, b1);  // P=kk+4
        PH_FULL(VMW3(), kk + 9, 3, kk + 7, b1, 0, af0, af1, b2);  // P=kk+5
    }
    // peel: phases 120..127 (last A stage = set 127 @P123; last B = 127 @P125)
    PH_FULL(VMW3(), 124, 4, 122, b2, 1, af1, af0, b0);            // P=120
    PH_FULL(VMW3(), 125, 5, 123, b0, 2, af0, af1, b1);            // P=121
    PH_FULL(VMW3(), 126, 0, 124, b1, 3, af1, af0, b2);            // P=122
    PH_FULL(VMW3(), 127, 1, 125, b2, 4, af0, af1, b0);            // P=123
    PH_NOSTAGE(VMW3(), 126, b0, 5, af1, af0, b1);                 // P=124
    PH_NOSTAGE(VMW2(), 127, b1, 0, af0, af1, b2);                 // P=125
    // P=126: no stage, no load; reads set 127 (buf 1)
    VMW2();
    BARRIER();
    SCHEDB();
    FRAG_READA(af1, 1);
    MFMA_SET(af0, b0);
    // P=127
    VMW0();
    BARRIER();
    SCHEDB();
    MFMA_SET(af1, b1);

    // epilogue: 32x32 C/D layout col=lane&31, row=(reg&3)+8*(reg>>2)+4*(lane>>5)
#pragma unroll
    for (int j = 0; j < 2; ++j) {
        const int o = bn * 128 + (wc2 + j) * 32 + (lane & 31);
        const int tt = t[o];
        const int sh = -nsh[o];
        const int mn = amin[o];
        const int mx = amax[o];
#pragma unroll
        for (int i = 0; i < 2; ++i) {
            const int rowbase = bm * 256 + (wr2 + i) * 32 + 4 * (lane >> 5);
#pragma unroll
            for (int r = 0; r < 16; ++r) {
                const int row = rowbase + (r & 3) + 8 * (r >> 2);
                int v = acc[i][j][r] + tt;
                v >>= sh;
                v = v < mn ? mn : (v > mx ? mx : v);
                __builtin_nontemporal_store(v, &out[(size_t)row * OUTDIM + o]);
            }
        }
    }
}

extern "C" void kernel_launch(void* const* d_in, const int* in_sizes, int n_in,
                              void* d_out, int out_size, void* d_ws, size_t ws_size,
                              hipStream_t stream) {
    const int* x = (const int*)d_in[0];
    const int* W = (const int*)d_in[1];
    const int* t = (const int*)d_in[2];
    const int* n = (const int*)d_in[3];
    const int* amin = (const int*)d_in[4];
    const int* amax = (const int*)d_in[5];
    int* out = (int*)d_out;

    uint8_t* xp = (uint8_t*)d_ws;                    // 33554432 B (fragment order)
    uint8_t* wp = xp + (size_t)BDIM * INDIM;         // 16777216 B (fragment order)

    pack_lds<<<1536, 256, 0, stream>>>(x, W, (uint32_t*)xp, (uint32_t*)wp);

    dim3 grid(OUTDIM / 128, BDIM / 256);  // (32 bn fast, 32 bm) = 1024 blocks
    gemm_lds<<<grid, 512, 0, stream>>>(xp, wp, t, n, amin, amax, out);
}